// Round 3
// baseline (808.577 us; speedup 1.0000x reference)
//
#include <hip/hip_runtime.h>
#include <hip/hip_bf16.h>

// TransformerBlock on MI355X (gfx950) — round 2: S^T-form flash attention
// (per-lane softmax scalars, b64/b128 P path, 128-wide KV tiles, reg prefetch,
// descending-q0 order). GEMMs unchanged from round 1 (32x32x16 MFMA).
// B=4 S=2048 D=1024 H=16 DK=64 DFF=4096. fp32 in/out, bf16 tensor-core compute.

typedef unsigned short u16;
typedef __attribute__((ext_vector_type(8))) short short8;    // 8 bf16 (MFMA A/B frag)
typedef __attribute__((ext_vector_type(4))) float f32x4;     // 16x16 C/D frag
typedef __attribute__((ext_vector_type(16))) float f32x16;   // 32x32 C/D frag

#define MFMA16(a, b, c) __builtin_amdgcn_mfma_f32_16x16x32_bf16(a, b, c, 0, 0, 0)
#define MFMA32(a, b, c) __builtin_amdgcn_mfma_f32_32x32x16_bf16(a, b, c, 0, 0, 0)

__device__ __forceinline__ u16 f2b(float f) {
  union { float f; unsigned u; } x; x.f = f;
  unsigned r = x.u + 0x7FFFu + ((x.u >> 16) & 1u);   // RNE
  return (u16)(r >> 16);
}
__device__ __forceinline__ float b2f(u16 h) {
  union { unsigned u; float f; } x; x.u = ((unsigned)h) << 16;
  return x.f;
}
__device__ __forceinline__ unsigned pkbf(float a, float b) {  // v_cvt_pk_bf16_f32
  __hip_bfloat162 h = __float22bfloat162_rn(make_float2(a, b));
  union { __hip_bfloat162 h; unsigned u; } cv; cv.h = h;
  return cv.u;
}
// async global->LDS, 16B per lane; LDS dest = wave-uniform base + lane*16.
__device__ __forceinline__ void async16(const void* g, void* l) {
  __builtin_amdgcn_global_load_lds(
      (const __attribute__((address_space(1))) void*)g,
      (__attribute__((address_space(3))) void*)l, 16, 0, 0);
}

// ---------------------------------------------------------------------------
// GEMM (bt-form): C[m,n] = sum_k A[m,k]*B[n,k] — unchanged from round 1.
// ---------------------------------------------------------------------------
template <int MODE>
__global__ __launch_bounds__(256, 2) void gemm_bt(
    const u16* __restrict__ A, const u16* __restrict__ B,
    u16* __restrict__ Cb, float* __restrict__ Cf, const float* __restrict__ R,
    int M, int N, int K) {
  __shared__ __align__(16) u16 As[128 * 64];
  __shared__ __align__(16) u16 Bs[128 * 64];
  const int tid = threadIdx.x;
  const int l = tid & 63, w = tid >> 6;
  const int wr = w & 1, wc = w >> 1;
  const int lr = l & 31, lh = l >> 5;
  const size_t m0 = (size_t)blockIdx.y * 128, n0 = (size_t)blockIdx.x * 128;
  f32x16 acc[2][2] = {};
  for (int k0 = 0; k0 < K; k0 += 64) {
#pragma unroll
    for (int t = 0; t < 4; ++t) {
      int c = t * 256 + tid;
      int r = c >> 3;
      int gc = ((c & 7) ^ (r & 7)) << 3;
      async16(A + (m0 + r) * (size_t)K + k0 + gc, &As[c * 8]);
    }
#pragma unroll
    for (int t = 0; t < 4; ++t) {
      int c = t * 256 + tid;
      int r = c >> 3;
      int gc = ((c & 7) ^ (r & 7)) << 3;
      async16(B + (n0 + r) * (size_t)K + k0 + gc, &Bs[c * 8]);
    }
    __syncthreads();
#pragma unroll
    for (int c = 0; c < 4; ++c) {
      const int c8 = c * 2 + lh;
      short8 af[2], bfr[2];
#pragma unroll
      for (int mi = 0; mi < 2; ++mi) {
        int r = wr * 64 + mi * 32 + lr;
        af[mi] = *(const short8*)&As[r * 64 + ((c8 ^ (r & 7)) << 3)];
      }
#pragma unroll
      for (int ni = 0; ni < 2; ++ni) {
        int r = wc * 64 + ni * 32 + lr;
        bfr[ni] = *(const short8*)&Bs[r * 64 + ((c8 ^ (r & 7)) << 3)];
      }
#pragma unroll
      for (int mi = 0; mi < 2; ++mi)
#pragma unroll
        for (int ni = 0; ni < 2; ++ni)
          acc[mi][ni] = MFMA32(af[mi], bfr[ni], acc[mi][ni]);
    }
    __syncthreads();
  }
#pragma unroll
  for (int mi = 0; mi < 2; ++mi)
#pragma unroll
    for (int ni = 0; ni < 2; ++ni) {
      size_t n = n0 + wc * 64 + ni * 32 + lr;
#pragma unroll
      for (int reg = 0; reg < 16; ++reg) {
        size_t m = m0 + wr * 64 + mi * 32 + (reg & 3) + 8 * (reg >> 2) + 4 * lh;
        float v = acc[mi][ni][reg];
        if (MODE == 0)
          Cb[m * (size_t)N + n] = f2b(v);
        else
          Cf[m * (size_t)N + n] = v + R[m * (size_t)N + n];
      }
    }
}

// ---------------------------------------------------------------------------
// Fused SwiGLU GEMM — unchanged from round 1.
// ---------------------------------------------------------------------------
__global__ __launch_bounds__(256, 2) void ffn_gemm(
    const u16* __restrict__ A, const u16* __restrict__ B1,
    const u16* __restrict__ B3, u16* __restrict__ Hout, int M, int N, int K) {
  __shared__ __align__(16) u16 As[128 * 64];
  __shared__ __align__(16) u16 B1s[128 * 64];
  __shared__ __align__(16) u16 B3s[128 * 64];
  const int tid = threadIdx.x;
  const int l = tid & 63, w = tid >> 6;
  const int wr = w & 1, wc = w >> 1;
  const int lr = l & 31, lh = l >> 5;
  const size_t m0 = (size_t)blockIdx.y * 128, n0 = (size_t)blockIdx.x * 128;
  f32x16 a1[2][2] = {}, a3[2][2] = {};
  for (int k0 = 0; k0 < K; k0 += 64) {
#pragma unroll
    for (int t = 0; t < 4; ++t) {
      int c = t * 256 + tid;
      int r = c >> 3;
      int gc = ((c & 7) ^ (r & 7)) << 3;
      async16(A + (m0 + r) * (size_t)K + k0 + gc, &As[c * 8]);
      async16(B1 + (n0 + r) * (size_t)K + k0 + gc, &B1s[c * 8]);
      async16(B3 + (n0 + r) * (size_t)K + k0 + gc, &B3s[c * 8]);
    }
    __syncthreads();
#pragma unroll
    for (int c = 0; c < 4; ++c) {
      const int c8 = c * 2 + lh;
      short8 af[2], b1f[2], b3f[2];
#pragma unroll
      for (int mi = 0; mi < 2; ++mi) {
        int r = wr * 64 + mi * 32 + lr;
        af[mi] = *(const short8*)&As[r * 64 + ((c8 ^ (r & 7)) << 3)];
      }
#pragma unroll
      for (int ni = 0; ni < 2; ++ni) {
        int r = wc * 64 + ni * 32 + lr;
        b1f[ni] = *(const short8*)&B1s[r * 64 + ((c8 ^ (r & 7)) << 3)];
        b3f[ni] = *(const short8*)&B3s[r * 64 + ((c8 ^ (r & 7)) << 3)];
      }
#pragma unroll
      for (int mi = 0; mi < 2; ++mi)
#pragma unroll
        for (int ni = 0; ni < 2; ++ni) {
          a1[mi][ni] = MFMA32(af[mi], b1f[ni], a1[mi][ni]);
          a3[mi][ni] = MFMA32(af[mi], b3f[ni], a3[mi][ni]);
        }
    }
    __syncthreads();
  }
#pragma unroll
  for (int mi = 0; mi < 2; ++mi)
#pragma unroll
    for (int ni = 0; ni < 2; ++ni) {
      size_t n = n0 + wc * 64 + ni * 32 + lr;
#pragma unroll
      for (int reg = 0; reg < 16; ++reg) {
        size_t m = m0 + wr * 64 + mi * 32 + (reg & 3) + 8 * (reg >> 2) + 4 * lh;
        float u = a1[mi][ni][reg];
        float g = u / (1.0f + __expf(-u));  // silu
        Hout[m * (size_t)N + n] = f2b(g * a3[mi][ni][reg]);
      }
    }
}

// ---------------------------------------------------------------------------
// Flash attention v2 (causal), S^T formulation.
// Block: 64 q-cols (4 waves x 16), KV tiles of 128, reg-prefetched staging.
// S^T = K·Q^T so each lane owns ONE q-column: softmax stats are lane scalars
// (2 shuffles), P rows pack as b64 writes / b128 reads.
// qh is prescaled by 0.125*log2(e) in rope_k -> softmax in exp2 domain.
// LDS strides: Ks 64 u16 (+XOR chunk swizzle), Vs/Ps 136 u16 (16B-aligned,
// 2-way banks under the 16-lane-phase model). Total 50.2 KB -> 3 blocks/CU.
// ---------------------------------------------------------------------------
__global__ __launch_bounds__(256, 3) void attn_k(
    const u16* __restrict__ qh, const u16* __restrict__ kh,
    const u16* __restrict__ vt, u16* __restrict__ aout) {
  __shared__ __align__(16) u16 Ks[128 * 64];
  __shared__ __align__(16) u16 Vs[64 * 136];
  __shared__ __align__(16) u16 Ps[64 * 136];
  const int tid = threadIdx.x;
  const int l = tid & 63, w = tid >> 6;
  const int q = l & 15, lq = l >> 4;
  const int q0 = (int)(gridDim.x - 1 - blockIdx.x) * 64;  // heavy blocks first
  const int bh = blockIdx.y;
  const size_t base = (size_t)bh * (2048 * 64);
  const int nt = (q0 + 64 + 127) >> 7;
  const int qcol = q0 + w * 16 + q;

  // B-frag of Q: lane owns column qcol; k = kk*32 + lq*8 + j
  short8 bq[2];
#pragma unroll
  for (int kk = 0; kk < 2; ++kk)
    bq[kk] = *(const short8*)(qh + base + (size_t)qcol * 64 + kk * 32 + lq * 8);

  // prefetch KV tile 0 into registers
  float4 pk[4], pv[4];
#pragma unroll
  for (int t = 0; t < 4; ++t) {
    int c = t * 256 + tid;
    pk[t] = *(const float4*)(kh + base + (size_t)(c >> 3) * 64 + (c & 7) * 8);
    pv[t] = *(const float4*)(vt + base + (size_t)(c >> 4) * 2048 + (c & 15) * 8);
  }

  f32x4 o[4] = {};
  float mI = -1e30f, lI = 0.0f;

  for (int it = 0; it < nt; ++it) {
    const int kv0 = it * 128;
    if (it) __syncthreads();  // WAR: all waves done with previous tile
#pragma unroll
    for (int t = 0; t < 4; ++t) {
      int c = t * 256 + tid;
      int r = c >> 3, ch = c & 7;
      *(float4*)&Ks[r * 64 + ((ch ^ (r & 7)) << 3)] = pk[t];
      *(float4*)&Vs[(c >> 4) * 136 + (c & 15) * 8] = pv[t];
    }
    __syncthreads();
    if (it + 1 < nt) {  // issue next-tile loads; latency hidden by compute
      const int kn = kv0 + 128;
#pragma unroll
      for (int t = 0; t < 4; ++t) {
        int c = t * 256 + tid;
        pk[t] = *(const float4*)(kh + base + (size_t)(kn + (c >> 3)) * 64 + (c & 7) * 8);
        pv[t] = *(const float4*)(vt + base + (size_t)(c >> 4) * 2048 + kn + (c & 15) * 8);
      }
    }
    // S^T = K · Q^T : 8 kv-tiles of 16
    f32x4 s[8] = {};
#pragma unroll
    for (int kk = 0; kk < 2; ++kk) {
#pragma unroll
      for (int mt = 0; mt < 8; ++mt) {
        int row = mt * 16 + q;
        short8 ak = *(const short8*)&Ks[row * 64 + (((kk * 4 + lq) ^ (q & 7)) << 3)];
        s[mt] = MFMA16(ak, bq[kk], s[mt]);
      }
    }
    if (it == nt - 1) {  // causal mask, diagonal tile only
#pragma unroll
      for (int mt = 0; mt < 8; ++mt)
#pragma unroll
        for (int r = 0; r < 4; ++r)
          if (kv0 + mt * 16 + lq * 4 + r > qcol) s[mt][r] = -1e30f;
    }
    // online softmax, exp2 domain, per-lane scalars
    float mx = -1e30f;
#pragma unroll
    for (int mt = 0; mt < 8; ++mt)
#pragma unroll
      for (int r = 0; r < 4; ++r) mx = fmaxf(mx, s[mt][r]);
    mx = fmaxf(mx, __shfl_xor(mx, 16, 64));
    mx = fmaxf(mx, __shfl_xor(mx, 32, 64));
    const float mn = fmaxf(mI, mx);
    const float al = exp2f(mI - mn);
    mI = mn;
    float rs = 0.0f;
#pragma unroll
    for (int mt = 0; mt < 8; ++mt)
#pragma unroll
      for (int r = 0; r < 4; ++r) {
        float p = exp2f(s[mt][r] - mn);
        s[mt][r] = p;
        rs += p;
      }
    rs += __shfl_xor(rs, 16, 64);
    rs += __shfl_xor(rs, 32, 64);
    lI = lI * al + rs;
#pragma unroll
    for (int mt = 0; mt < 4; ++mt)
#pragma unroll
      for (int r = 0; r < 4; ++r) o[mt][r] *= al;
    // P^T (C-layout) -> Ps[q-local][kv]: lane's 4 consecutive kv -> b64 write
    u16* pr = &Ps[(w * 16 + q) * 136];
#pragma unroll
    for (int mt = 0; mt < 8; ++mt) {
      uint2 pd;
      pd.x = pkbf(s[mt][0], s[mt][1]);
      pd.y = pkbf(s[mt][2], s[mt][3]);
      *(uint2*)&pr[mt * 16 + lq * 4] = pd;
    }
    // O^T += V^T · P^T  (wave-private Ps: no barrier, lgkmcnt orders it)
#pragma unroll
    for (int kk = 0; kk < 4; ++kk) {
      short8 bp = *(const short8*)&pr[kk * 32 + lq * 8];
#pragma unroll
      for (int mt = 0; mt < 4; ++mt) {
        short8 av = *(const short8*)&Vs[(mt * 16 + q) * 136 + (kk * 4 + lq) * 8];
        o[mt] = MFMA16(av, bp, o[mt]);
      }
    }
  }
  // epilogue: lane owns column qcol; rows d = mt*16 + lq*4 + r
  const int b = bh >> 4, h = bh & 15;
  const float inv = 1.0f / lI;
#pragma unroll
  for (int mt = 0; mt < 4; ++mt) {
    uint2 pd;
    pd.x = pkbf(o[mt][0] * inv, o[mt][1] * inv);
    pd.y = pkbf(o[mt][2] * inv, o[mt][3] * inv);
    *(uint2*)&aout[((size_t)(b * 2048 + qcol)) * 1024 + h * 64 + mt * 16 + lq * 4] = pd;
  }
}

// ---------------------------------------------------------------------------
// Elementwise helpers
// ---------------------------------------------------------------------------
__global__ __launch_bounds__(256) void rmsnorm_k(
    const float* __restrict__ x, const float* __restrict__ w, u16* __restrict__ out) {
  const int row = blockIdx.x;
  const int tid = threadIdx.x;
  const float4 v = ((const float4*)(x + (size_t)row * 1024))[tid];
  float ss = v.x * v.x + v.y * v.y + v.z * v.z + v.w * v.w;
#pragma unroll
  for (int d = 1; d < 64; d <<= 1) ss += __shfl_xor(ss, d, 64);
  __shared__ float red[4];
  if ((tid & 63) == 0) red[tid >> 6] = ss;
  __syncthreads();
  const float sc = rsqrtf((red[0] + red[1] + red[2] + red[3]) * (1.0f / 1024.0f) + 1e-5f);
  const float4 wv = ((const float4*)w)[tid];
  u16* o = out + (size_t)row * 1024 + tid * 4;
  o[0] = f2b(v.x * sc * wv.x);
  o[1] = f2b(v.y * sc * wv.y);
  o[2] = f2b(v.z * sc * wv.z);
  o[3] = f2b(v.w * sc * wv.w);
}

// RoPE for q AND k from fused QKV [8192][3072] -> QH/KH [b][h][s][64].
// Q is prescaled by 0.125*log2(e) so attention scores are exp2-domain ready.
__global__ __launch_bounds__(256) void rope_k(
    const u16* __restrict__ qkv, u16* __restrict__ qh, u16* __restrict__ kh,
    const int* __restrict__ pos) {
  int idx = blockIdx.x * 256 + threadIdx.x;
  int pr = idx & 1023;
  int row = idx >> 10;
  int which = pr >> 9;  // 0=q, 1=k
  int p = pr & 511;
  int s = row & 2047, b = row >> 11;
  int h = p >> 5, i = p & 31;
  size_t si = (size_t)row * 3072 + which * 1024 + h * 64 + 2 * i;
  float xe = b2f(qkv[si]), xo = b2f(qkv[si + 1]);
  float inv = exp2f(-(float)(2 * i) * (13.287712379549449f / 64.0f));
  float ang = (float)pos[s] * inv;
  float sn, cs;
  __sincosf(ang, &sn, &cs);
  const float scale = which ? 1.0f : 0.18033688011112042f;  // 0.125*log2(e)
  u16* dst = which ? kh : qh;
  size_t od = (((size_t)(b * 16 + h)) * 2048 + s) * 64 + 2 * i;
  dst[od] = f2b((xe * cs - xo * sn) * scale);
  dst[od + 1] = f2b((xe * sn + xo * cs) * scale);
}

// v (cols 2048..3071 of QKV) -> vT [b][h][d][s], 64x64 LDS tile transpose
__global__ __launch_bounds__(256) void transv_k(
    const u16* __restrict__ qkv, u16* __restrict__ vt) {
  __shared__ u16 t[64][65];
  const int bh = blockIdx.y, s0 = blockIdx.x * 64;
  const int b = bh >> 4, h = bh & 15;
  const int tid = threadIdx.x;
#pragma unroll
  for (int i = 0; i < 16; ++i) {
    int e = i * 256 + tid;
    int sl = e >> 6, d = e & 63;
    t[sl][d] = qkv[((size_t)(b * 2048 + s0 + sl)) * 3072 + 2048 + h * 64 + d];
  }
  __syncthreads();
#pragma unroll
  for (int i = 0; i < 16; ++i) {
    int e = i * 256 + tid;
    int d = e >> 6, sl = e & 63;
    vt[((size_t)(bh * 64 + d)) * 2048 + s0 + sl] = t[sl][d];
  }
}

__global__ __launch_bounds__(256) void cvt_k(
    const float* __restrict__ in, u16* __restrict__ out, int n4) {
  int i = blockIdx.x * 256 + threadIdx.x;
  if (i < n4) {
    float4 v = ((const float4*)in)[i];
    u16* o = out + (size_t)i * 4;
    o[0] = f2b(v.x); o[1] = f2b(v.y); o[2] = f2b(v.z); o[3] = f2b(v.w);
  }
}

// ---------------------------------------------------------------------------
extern "C" void kernel_launch(void* const* d_in, const int* in_sizes, int n_in,
                              void* d_out, int out_size, void* d_ws, size_t ws_size,
                              hipStream_t stream) {
  const float* x   = (const float*)d_in[0];
  const int*   pos = (const int*)d_in[1];
  const float* qp  = (const float*)d_in[2];
  const float* kp  = (const float*)d_in[3];
  const float* vp  = (const float*)d_in[4];
  const float* op  = (const float*)d_in[5];
  const float* w1  = (const float*)d_in[6];
  const float* w2  = (const float*)d_in[7];   // dict order: w2 before w3
  const float* w3  = (const float*)d_in[8];
  const float* ln1 = (const float*)d_in[9];
  const float* ln2 = (const float*)d_in[10];
  float* out = (float*)d_out;
  char* ws = (char*)d_ws;
  const size_t MB = 1024 * 1024;

  u16* WQKV = (u16*)(ws + 0 * MB);    // [3072][1024] stacked q,k,v  (6 MB)
  u16* WO   = (u16*)(ws + 6 * MB);
  u16* W1   = (u16*)(ws + 8 * MB);
  u16* W3   = (u16*)(ws + 16 * MB);
  u16* W2   = (u16*)(ws + 24 * MB);
  u16* XLN  = (u16*)(ws + 32 * MB);
  u16* QKV  = (u16*)(ws + 48 * MB);   // [8192][3072]  (48..96 MB)
  u16* QH   = (u16*)(ws + 96 * MB);
  u16* KH   = (u16*)(ws + 112 * MB);
  u16* VT   = (u16*)(ws + 128 * MB);
  u16* ATT  = (u16*)(ws + 48 * MB);   // reuses QKV
  u16* XLN2 = (u16*)(ws + 64 * MB);
  u16* Hbuf = (u16*)(ws + 80 * MB);   // 64 MB (VT dead by then)
  (void)in_sizes; (void)n_in; (void)out_size; (void)ws_size;

  cvt_k<<<1024, 256, 0, stream>>>(qp, WQKV, 262144);
  cvt_k<<<1024, 256, 0, stream>>>(kp, WQKV + 1024 * 1024, 262144);
  cvt_k<<<1024, 256, 0, stream>>>(vp, WQKV + 2 * 1024 * 1024, 262144);
  cvt_k<<<1024, 256, 0, stream>>>(op, WO, 262144);
  cvt_k<<<4096, 256, 0, stream>>>(w1, W1, 1048576);
  cvt_k<<<4096, 256, 0, stream>>>(w3, W3, 1048576);
  cvt_k<<<4096, 256, 0, stream>>>(w2, W2, 1048576);
  rmsnorm_k<<<8192, 256, 0, stream>>>(x, ln1, XLN);
  gemm_bt<0><<<dim3(24, 64), 256, 0, stream>>>(XLN, WQKV, QKV, nullptr, nullptr, 8192, 3072, 1024);
  rope_k<<<32768, 256, 0, stream>>>(QKV, QH, KH, pos);
  transv_k<<<dim3(32, 64), 256, 0, stream>>>(QKV, VT);
  attn_k<<<dim3(32, 64), 256, 0, stream>>>(QH, KH, VT, ATT);
  gemm_bt<1><<<dim3(8, 64), 256, 0, stream>>>(ATT, WO, nullptr, out, x, 8192, 1024, 1024);
  rmsnorm_k<<<8192, 256, 0, stream>>>(out, ln2, XLN2);
  ffn_gemm<<<dim3(32, 64), 256, 0, stream>>>(XLN2, W1, W3, Hbuf, 8192, 4096, 1024);
  gemm_bt<1><<<dim3(8, 64), 256, 0, stream>>>(Hbuf, W2, nullptr, out, out, 8192, 1024, 4096);
}

// Round 4
// 641.430 us; speedup vs baseline: 1.2606x; 1.2606x over previous
//
#include <hip/hip_runtime.h>
#include <hip/hip_bf16.h>

// TransformerBlock on MI355X (gfx950) — round 3: S^T flash attention with
// async16 (global_load_lds) staging, no reg prefetch (R2 spilled: WRITE_SIZE
// 342MB), no manual b128 LDS writes (R2: 7.8M bank conflicts).
// GEMMs unchanged from round 1 (32x32x16 MFMA).
// B=4 S=2048 D=1024 H=16 DK=64 DFF=4096. fp32 in/out, bf16 tensor-core compute.

typedef unsigned short u16;
typedef __attribute__((ext_vector_type(8))) short short8;    // 8 bf16 (MFMA A/B frag)
typedef __attribute__((ext_vector_type(4))) float f32x4;     // 16x16 C/D frag
typedef __attribute__((ext_vector_type(16))) float f32x16;   // 32x32 C/D frag

#define MFMA16(a, b, c) __builtin_amdgcn_mfma_f32_16x16x32_bf16(a, b, c, 0, 0, 0)
#define MFMA32(a, b, c) __builtin_amdgcn_mfma_f32_32x32x16_bf16(a, b, c, 0, 0, 0)

__device__ __forceinline__ u16 f2b(float f) {
  union { float f; unsigned u; } x; x.f = f;
  unsigned r = x.u + 0x7FFFu + ((x.u >> 16) & 1u);   // RNE
  return (u16)(r >> 16);
}
__device__ __forceinline__ float b2f(u16 h) {
  union { unsigned u; float f; } x; x.u = ((unsigned)h) << 16;
  return x.f;
}
__device__ __forceinline__ unsigned pkbf(float a, float b) {
  __hip_bfloat162 h = __float22bfloat162_rn(make_float2(a, b));
  union { __hip_bfloat162 h; unsigned u; } cv; cv.h = h;
  return cv.u;
}
// async global->LDS, 16B per lane; LDS dest = wave-uniform base + lane*16.
__device__ __forceinline__ void async16(const void* g, void* l) {
  __builtin_amdgcn_global_load_lds(
      (const __attribute__((address_space(1))) void*)g,
      (__attribute__((address_space(3))) void*)l, 16, 0, 0);
}

// ---------------------------------------------------------------------------
// GEMM (bt-form): C[m,n] = sum_k A[m,k]*B[n,k] — unchanged from round 1.
// ---------------------------------------------------------------------------
template <int MODE>
__global__ __launch_bounds__(256, 2) void gemm_bt(
    const u16* __restrict__ A, const u16* __restrict__ B,
    u16* __restrict__ Cb, float* __restrict__ Cf, const float* __restrict__ R,
    int M, int N, int K) {
  __shared__ __align__(16) u16 As[128 * 64];
  __shared__ __align__(16) u16 Bs[128 * 64];
  const int tid = threadIdx.x;
  const int l = tid & 63, w = tid >> 6;
  const int wr = w & 1, wc = w >> 1;
  const int lr = l & 31, lh = l >> 5;
  const size_t m0 = (size_t)blockIdx.y * 128, n0 = (size_t)blockIdx.x * 128;
  f32x16 acc[2][2] = {};
  for (int k0 = 0; k0 < K; k0 += 64) {
#pragma unroll
    for (int t = 0; t < 4; ++t) {
      int c = t * 256 + tid;
      int r = c >> 3;
      int gc = ((c & 7) ^ (r & 7)) << 3;
      async16(A + (m0 + r) * (size_t)K + k0 + gc, &As[c * 8]);
    }
#pragma unroll
    for (int t = 0; t < 4; ++t) {
      int c = t * 256 + tid;
      int r = c >> 3;
      int gc = ((c & 7) ^ (r & 7)) << 3;
      async16(B + (n0 + r) * (size_t)K + k0 + gc, &Bs[c * 8]);
    }
    __syncthreads();
#pragma unroll
    for (int c = 0; c < 4; ++c) {
      const int c8 = c * 2 + lh;
      short8 af[2], bfr[2];
#pragma unroll
      for (int mi = 0; mi < 2; ++mi) {
        int r = wr * 64 + mi * 32 + lr;
        af[mi] = *(const short8*)&As[r * 64 + ((c8 ^ (r & 7)) << 3)];
      }
#pragma unroll
      for (int ni = 0; ni < 2; ++ni) {
        int r = wc * 64 + ni * 32 + lr;
        bfr[ni] = *(const short8*)&Bs[r * 64 + ((c8 ^ (r & 7)) << 3)];
      }
#pragma unroll
      for (int mi = 0; mi < 2; ++mi)
#pragma unroll
        for (int ni = 0; ni < 2; ++ni)
          acc[mi][ni] = MFMA32(af[mi], bfr[ni], acc[mi][ni]);
    }
    __syncthreads();
  }
#pragma unroll
  for (int mi = 0; mi < 2; ++mi)
#pragma unroll
    for (int ni = 0; ni < 2; ++ni) {
      size_t n = n0 + wc * 64 + ni * 32 + lr;
#pragma unroll
      for (int reg = 0; reg < 16; ++reg) {
        size_t m = m0 + wr * 64 + mi * 32 + (reg & 3) + 8 * (reg >> 2) + 4 * lh;
        float v = acc[mi][ni][reg];
        if (MODE == 0)
          Cb[m * (size_t)N + n] = f2b(v);
        else
          Cf[m * (size_t)N + n] = v + R[m * (size_t)N + n];
      }
    }
}

// ---------------------------------------------------------------------------
// Fused SwiGLU GEMM — unchanged from round 1.
// ---------------------------------------------------------------------------
__global__ __launch_bounds__(256, 2) void ffn_gemm(
    const u16* __restrict__ A, const u16* __restrict__ B1,
    const u16* __restrict__ B3, u16* __restrict__ Hout, int M, int N, int K) {
  __shared__ __align__(16) u16 As[128 * 64];
  __shared__ __align__(16) u16 B1s[128 * 64];
  __shared__ __align__(16) u16 B3s[128 * 64];
  const int tid = threadIdx.x;
  const int l = tid & 63, w = tid >> 6;
  const int wr = w & 1, wc = w >> 1;
  const int lr = l & 31, lh = l >> 5;
  const size_t m0 = (size_t)blockIdx.y * 128, n0 = (size_t)blockIdx.x * 128;
  f32x16 a1[2][2] = {}, a3[2][2] = {};
  for (int k0 = 0; k0 < K; k0 += 64) {
#pragma unroll
    for (int t = 0; t < 4; ++t) {
      int c = t * 256 + tid;
      int r = c >> 3;
      int gc = ((c & 7) ^ (r & 7)) << 3;
      async16(A + (m0 + r) * (size_t)K + k0 + gc, &As[c * 8]);
      async16(B1 + (n0 + r) * (size_t)K + k0 + gc, &B1s[c * 8]);
      async16(B3 + (n0 + r) * (size_t)K + k0 + gc, &B3s[c * 8]);
    }
    __syncthreads();
#pragma unroll
    for (int c = 0; c < 4; ++c) {
      const int c8 = c * 2 + lh;
      short8 af[2], b1f[2], b3f[2];
#pragma unroll
      for (int mi = 0; mi < 2; ++mi) {
        int r = wr * 64 + mi * 32 + lr;
        af[mi] = *(const short8*)&As[r * 64 + ((c8 ^ (r & 7)) << 3)];
      }
#pragma unroll
      for (int ni = 0; ni < 2; ++ni) {
        int r = wc * 64 + ni * 32 + lr;
        b1f[ni] = *(const short8*)&B1s[r * 64 + ((c8 ^ (r & 7)) << 3)];
        b3f[ni] = *(const short8*)&B3s[r * 64 + ((c8 ^ (r & 7)) << 3)];
      }
#pragma unroll
      for (int mi = 0; mi < 2; ++mi)
#pragma unroll
        for (int ni = 0; ni < 2; ++ni) {
          a1[mi][ni] = MFMA32(af[mi], b1f[ni], a1[mi][ni]);
          a3[mi][ni] = MFMA32(af[mi], b3f[ni], a3[mi][ni]);
        }
    }
    __syncthreads();
  }
#pragma unroll
  for (int mi = 0; mi < 2; ++mi)
#pragma unroll
    for (int ni = 0; ni < 2; ++ni) {
      size_t n = n0 + wc * 64 + ni * 32 + lr;
#pragma unroll
      for (int reg = 0; reg < 16; ++reg) {
        size_t m = m0 + wr * 64 + mi * 32 + (reg & 3) + 8 * (reg >> 2) + 4 * lh;
        float u = a1[mi][ni][reg];
        float g = u / (1.0f + __expf(-u));  // silu
        Hout[m * (size_t)N + n] = f2b(g * a3[mi][ni][reg]);
      }
    }
}

// ---------------------------------------------------------------------------
// Flash attention v3 (causal), S^T formulation, async16 staging.
// Block: 64 q-cols (4 waves x 16), KV tiles of 128.
// S^T = K·Q^T: lane owns ONE q-column -> softmax stats are lane scalars.
// Staging via global_load_lds (zero bank conflicts, no VGPR round-trip).
// Ks: 128x64, chunk-XOR r&7.  Vs: 64x128, chunk-XOR r&15 (16 chunks/row);
// read phase (16 lanes) covers 32 banks 2x -> free. Ps: stride 136, VALU
// b64 writes / own-row b128 reads. LDS 49KB -> 3 blocks/CU.
// ---------------------------------------------------------------------------
__global__ __launch_bounds__(256, 2) void attn_k(
    const u16* __restrict__ qh, const u16* __restrict__ kh,
    const u16* __restrict__ vt, u16* __restrict__ aout) {
  __shared__ __align__(16) u16 Ks[128 * 64];
  __shared__ __align__(16) u16 Vs[64 * 128];
  __shared__ __align__(16) u16 Ps[64 * 136];
  const int tid = threadIdx.x;
  const int l = tid & 63, w = tid >> 6;
  const int q = l & 15, lq = l >> 4;
  const int q0 = (int)(gridDim.x - 1 - blockIdx.x) * 64;  // heavy blocks first
  const int bh = blockIdx.y;
  const size_t base = (size_t)bh * (2048 * 64);
  const int nt = (q0 + 64 + 127) >> 7;
  const int qcol = q0 + w * 16 + q;

  // B-frag of Q: lane owns column qcol; k = kk*32 + lq*8 + j
  short8 bq[2];
#pragma unroll
  for (int kk = 0; kk < 2; ++kk)
    bq[kk] = *(const short8*)(qh + base + (size_t)qcol * 64 + kk * 32 + lq * 8);

  f32x4 o[4] = {};
  float mI = -1e30f, lI = 0.0f;

  for (int it = 0; it < nt; ++it) {
    const int kv0 = it << 7;
    if (it) __syncthreads();  // WAR: all waves done with previous tile
    // stage K (128x64) + V^T (64x128), XOR-swizzled, via async16
#pragma unroll
    for (int t = 0; t < 4; ++t) {
      int p = t * 256 + tid;
      int r = p >> 3, cs = p & 7;
      async16(kh + base + (size_t)(kv0 + r) * 64 + ((cs ^ (r & 7)) << 3), &Ks[p * 8]);
    }
#pragma unroll
    for (int t = 0; t < 4; ++t) {
      int p = t * 256 + tid;
      int r = p >> 4, cs = p & 15;
      async16(vt + base + (size_t)r * 2048 + kv0 + ((cs ^ (r & 15)) << 3), &Vs[p * 8]);
    }
    __syncthreads();
    // S^T = K · Q^T : 8 kv-subtiles of 16
    f32x4 s[8] = {};
#pragma unroll
    for (int kk = 0; kk < 2; ++kk) {
#pragma unroll
      for (int mt = 0; mt < 8; ++mt) {
        int row = mt * 16 + q;
        short8 ak = *(const short8*)&Ks[row * 64 + (((kk * 4 + lq) ^ (q & 7)) << 3)];
        s[mt] = MFMA16(ak, bq[kk], s[mt]);
      }
    }
    if (it == nt - 1) {  // causal mask, diagonal tile only
#pragma unroll
      for (int mt = 0; mt < 8; ++mt)
#pragma unroll
        for (int r = 0; r < 4; ++r)
          if (kv0 + mt * 16 + lq * 4 + r > qcol) s[mt][r] = -1e30f;
    }
    // online softmax, exp2 domain, per-lane scalars (Q prescaled in rope_k)
    float mx = -1e30f;
#pragma unroll
    for (int mt = 0; mt < 8; ++mt)
#pragma unroll
      for (int r = 0; r < 4; ++r) mx = fmaxf(mx, s[mt][r]);
    mx = fmaxf(mx, __shfl_xor(mx, 16, 64));
    mx = fmaxf(mx, __shfl_xor(mx, 32, 64));
    const float mn = fmaxf(mI, mx);
    const float al = exp2f(mI - mn);
    mI = mn;
    float rs = 0.0f;
#pragma unroll
    for (int mt = 0; mt < 8; ++mt)
#pragma unroll
      for (int r = 0; r < 4; ++r) {
        float p = exp2f(s[mt][r] - mn);
        s[mt][r] = p;
        rs += p;
      }
    rs += __shfl_xor(rs, 16, 64);
    rs += __shfl_xor(rs, 32, 64);
    lI = lI * al + rs;
#pragma unroll
    for (int mt = 0; mt < 4; ++mt)
#pragma unroll
      for (int r = 0; r < 4; ++r) o[mt][r] *= al;
    // P^T (C-layout) -> Ps[q-local][kv]: lane's 4 consecutive kv -> b64 write
    u16* pr = &Ps[(w * 16 + q) * 136];
#pragma unroll
    for (int mt = 0; mt < 8; ++mt) {
      uint2 pd;
      pd.x = pkbf(s[mt][0], s[mt][1]);
      pd.y = pkbf(s[mt][2], s[mt][3]);
      *(uint2*)&pr[mt * 16 + lq * 4] = pd;
    }
    // O^T += V^T · P^T  (wave-private Ps rows: lgkmcnt orders it, no barrier)
#pragma unroll
    for (int kk = 0; kk < 4; ++kk) {
      short8 bp = *(const short8*)&pr[kk * 32 + lq * 8];
#pragma unroll
      for (int mt = 0; mt < 4; ++mt) {
        int row = mt * 16 + q;
        short8 av = *(const short8*)&Vs[row * 128 + (((kk * 4 + lq) ^ (row & 15)) << 3)];
        o[mt] = MFMA16(av, bp, o[mt]);
      }
    }
  }
  // epilogue: lane owns column qcol; rows d = mt*16 + lq*4 + r
  const int b = bh >> 4, h = bh & 15;
  const float inv = 1.0f / lI;
#pragma unroll
  for (int mt = 0; mt < 4; ++mt) {
    uint2 pd;
    pd.x = pkbf(o[mt][0] * inv, o[mt][1] * inv);
    pd.y = pkbf(o[mt][2] * inv, o[mt][3] * inv);
    *(uint2*)&aout[((size_t)(b * 2048 + qcol)) * 1024 + h * 64 + mt * 16 + lq * 4] = pd;
  }
}

// ---------------------------------------------------------------------------
// Elementwise helpers
// ---------------------------------------------------------------------------
__global__ __launch_bounds__(256) void rmsnorm_k(
    const float* __restrict__ x, const float* __restrict__ w, u16* __restrict__ out) {
  const int row = blockIdx.x;
  const int tid = threadIdx.x;
  const float4 v = ((const float4*)(x + (size_t)row * 1024))[tid];
  float ss = v.x * v.x + v.y * v.y + v.z * v.z + v.w * v.w;
#pragma unroll
  for (int d = 1; d < 64; d <<= 1) ss += __shfl_xor(ss, d, 64);
  __shared__ float red[4];
  if ((tid & 63) == 0) red[tid >> 6] = ss;
  __syncthreads();
  const float sc = rsqrtf((red[0] + red[1] + red[2] + red[3]) * (1.0f / 1024.0f) + 1e-5f);
  const float4 wv = ((const float4*)w)[tid];
  u16* o = out + (size_t)row * 1024 + tid * 4;
  o[0] = f2b(v.x * sc * wv.x);
  o[1] = f2b(v.y * sc * wv.y);
  o[2] = f2b(v.z * sc * wv.z);
  o[3] = f2b(v.w * sc * wv.w);
}

// RoPE for q AND k from fused QKV [8192][3072] -> QH/KH [b][h][s][64].
// Q is prescaled by 0.125*log2(e) so attention scores are exp2-domain ready.
__global__ __launch_bounds__(256) void rope_k(
    const u16* __restrict__ qkv, u16* __restrict__ qh, u16* __restrict__ kh,
    const int* __restrict__ pos) {
  int idx = blockIdx.x * 256 + threadIdx.x;
  int pr = idx & 1023;
  int row = idx >> 10;
  int which = pr >> 9;  // 0=q, 1=k
  int p = pr & 511;
  int s = row & 2047, b = row >> 11;
  int h = p >> 5, i = p & 31;
  size_t si = (size_t)row * 3072 + which * 1024 + h * 64 + 2 * i;
  float xe = b2f(qkv[si]), xo = b2f(qkv[si + 1]);
  float inv = exp2f(-(float)(2 * i) * (13.287712379549449f / 64.0f));
  float ang = (float)pos[s] * inv;
  float sn, cs;
  __sincosf(ang, &sn, &cs);
  const float scale = which ? 1.0f : 0.18033688011112042f;  // 0.125*log2(e)
  u16* dst = which ? kh : qh;
  size_t od = (((size_t)(b * 16 + h)) * 2048 + s) * 64 + 2 * i;
  dst[od] = f2b((xe * cs - xo * sn) * scale);
  dst[od + 1] = f2b((xe * sn + xo * cs) * scale);
}

// v (cols 2048..3071 of QKV) -> vT [b][h][d][s], 64x64 LDS tile transpose
__global__ __launch_bounds__(256) void transv_k(
    const u16* __restrict__ qkv, u16* __restrict__ vt) {
  __shared__ u16 t[64][65];
  const int bh = blockIdx.y, s0 = blockIdx.x * 64;
  const int b = bh >> 4, h = bh & 15;
  const int tid = threadIdx.x;
#pragma unroll
  for (int i = 0; i < 16; ++i) {
    int e = i * 256 + tid;
    int sl = e >> 6, d = e & 63;
    t[sl][d] = qkv[((size_t)(b * 2048 + s0 + sl)) * 3072 + 2048 + h * 64 + d];
  }
  __syncthreads();
#pragma unroll
  for (int i = 0; i < 16; ++i) {
    int e = i * 256 + tid;
    int d = e >> 6, sl = e & 63;
    vt[((size_t)(bh * 64 + d)) * 2048 + s0 + sl] = t[sl][d];
  }
}

__global__ __launch_bounds__(256) void cvt_k(
    const float* __restrict__ in, u16* __restrict__ out, int n4) {
  int i = blockIdx.x * 256 + threadIdx.x;
  if (i < n4) {
    float4 v = ((const float4*)in)[i];
    u16* o = out + (size_t)i * 4;
    o[0] = f2b(v.x); o[1] = f2b(v.y); o[2] = f2b(v.z); o[3] = f2b(v.w);
  }
}

// ---------------------------------------------------------------------------
extern "C" void kernel_launch(void* const* d_in, const int* in_sizes, int n_in,
                              void* d_out, int out_size, void* d_ws, size_t ws_size,
                              hipStream_t stream) {
  const float* x   = (const float*)d_in[0];
  const int*   pos = (const int*)d_in[1];
  const float* qp  = (const float*)d_in[2];
  const float* kp  = (const float*)d_in[3];
  const float* vp  = (const float*)d_in[4];
  const float* op  = (const float*)d_in[5];
  const float* w1  = (const float*)d_in[6];
  const float* w2  = (const float*)d_in[7];   // dict order: w2 before w3
  const float* w3  = (const float*)d_in[8];
  const float* ln1 = (const float*)d_in[9];
  const float* ln2 = (const float*)d_in[10];
  float* out = (float*)d_out;
  char* ws = (char*)d_ws;
  const size_t MB = 1024 * 1024;

  u16* WQKV = (u16*)(ws + 0 * MB);    // [3072][1024] stacked q,k,v  (6 MB)
  u16* WO   = (u16*)(ws + 6 * MB);
  u16* W1   = (u16*)(ws + 8 * MB);
  u16* W3   = (u16*)(ws + 16 * MB);
  u16* W2   = (u16*)(ws + 24 * MB);
  u16* XLN  = (u16*)(ws + 32 * MB);
  u16* QKV  = (u16*)(ws + 48 * MB);   // [8192][3072]  (48..96 MB)
  u16* QH   = (u16*)(ws + 96 * MB);
  u16* KH   = (u16*)(ws + 112 * MB);
  u16* VT   = (u16*)(ws + 128 * MB);
  u16* ATT  = (u16*)(ws + 48 * MB);   // reuses QKV
  u16* XLN2 = (u16*)(ws + 64 * MB);
  u16* Hbuf = (u16*)(ws + 80 * MB);   // 64 MB (VT dead by then)
  (void)in_sizes; (void)n_in; (void)out_size; (void)ws_size;

  cvt_k<<<1024, 256, 0, stream>>>(qp, WQKV, 262144);
  cvt_k<<<1024, 256, 0, stream>>>(kp, WQKV + 1024 * 1024, 262144);
  cvt_k<<<1024, 256, 0, stream>>>(vp, WQKV + 2 * 1024 * 1024, 262144);
  cvt_k<<<1024, 256, 0, stream>>>(op, WO, 262144);
  cvt_k<<<4096, 256, 0, stream>>>(w1, W1, 1048576);
  cvt_k<<<4096, 256, 0, stream>>>(w3, W3, 1048576);
  cvt_k<<<4096, 256, 0, stream>>>(w2, W2, 1048576);
  rmsnorm_k<<<8192, 256, 0, stream>>>(x, ln1, XLN);
  gemm_bt<0><<<dim3(24, 64), 256, 0, stream>>>(XLN, WQKV, QKV, nullptr, nullptr, 8192, 3072, 1024);
  rope_k<<<32768, 256, 0, stream>>>(QKV, QH, KH, pos);
  transv_k<<<dim3(32, 64), 256, 0, stream>>>(QKV, VT);
  attn_k<<<dim3(32, 64), 256, 0, stream>>>(QH, KH, VT, ATT);
  gemm_bt<1><<<dim3(8, 64), 256, 0, stream>>>(ATT, WO, nullptr, out, x, 8192, 1024, 1024);
  rmsnorm_k<<<8192, 256, 0, stream>>>(out, ln2, XLN2);
  ffn_gemm<<<dim3(32, 64), 256, 0, stream>>>(XLN2, W1, W3, Hbuf, 8192, 4096, 1024);
  gemm_bt<1><<<dim3(8, 64), 256, 0, stream>>>(Hbuf, W2, nullptr, out, out, 8192, 1024, 4096);
}

// Round 5
// 629.141 us; speedup vs baseline: 1.2852x; 1.0195x over previous
//
#include <hip/hip_runtime.h>
#include <hip/hip_bf16.h>

// TransformerBlock on MI355X (gfx950) — round 4: attn q-tile 128 (2 q-subtiles
// per wave share one K/V stage), fused weight-cvt kernel, vectorized rope.
// GEMMs unchanged from R3 (m97-plateau: 877 TF measured).
// B=4 S=2048 D=1024 H=16 DK=64 DFF=4096. fp32 in/out, bf16 tensor-core compute.

typedef unsigned short u16;
typedef __attribute__((ext_vector_type(8))) short short8;    // 8 bf16 (MFMA A/B frag)
typedef __attribute__((ext_vector_type(4))) float f32x4;     // 16x16 C/D frag
typedef __attribute__((ext_vector_type(16))) float f32x16;   // 32x32 C/D frag

#define MFMA16(a, b, c) __builtin_amdgcn_mfma_f32_16x16x32_bf16(a, b, c, 0, 0, 0)
#define MFMA32(a, b, c) __builtin_amdgcn_mfma_f32_32x32x16_bf16(a, b, c, 0, 0, 0)

__device__ __forceinline__ u16 f2b(float f) {
  union { float f; unsigned u; } x; x.f = f;
  unsigned r = x.u + 0x7FFFu + ((x.u >> 16) & 1u);   // RNE
  return (u16)(r >> 16);
}
__device__ __forceinline__ float b2f(u16 h) {
  union { unsigned u; float f; } x; x.u = ((unsigned)h) << 16;
  return x.f;
}
__device__ __forceinline__ unsigned pkbf(float a, float b) {
  __hip_bfloat162 h = __float22bfloat162_rn(make_float2(a, b));
  union { __hip_bfloat162 h; unsigned u; } cv; cv.h = h;
  return cv.u;
}
// async global->LDS, 16B per lane; LDS dest = wave-uniform base + lane*16.
__device__ __forceinline__ void async16(const void* g, void* l) {
  __builtin_amdgcn_global_load_lds(
      (const __attribute__((address_space(1))) void*)g,
      (__attribute__((address_space(3))) void*)l, 16, 0, 0);
}

// ---------------------------------------------------------------------------
// GEMM (bt-form): C[m,n] = sum_k A[m,k]*B[n,k] — unchanged from round 1.
// ---------------------------------------------------------------------------
template <int MODE>
__global__ __launch_bounds__(256, 2) void gemm_bt(
    const u16* __restrict__ A, const u16* __restrict__ B,
    u16* __restrict__ Cb, float* __restrict__ Cf, const float* __restrict__ R,
    int M, int N, int K) {
  __shared__ __align__(16) u16 As[128 * 64];
  __shared__ __align__(16) u16 Bs[128 * 64];
  const int tid = threadIdx.x;
  const int l = tid & 63, w = tid >> 6;
  const int wr = w & 1, wc = w >> 1;
  const int lr = l & 31, lh = l >> 5;
  const size_t m0 = (size_t)blockIdx.y * 128, n0 = (size_t)blockIdx.x * 128;
  f32x16 acc[2][2] = {};
  for (int k0 = 0; k0 < K; k0 += 64) {
#pragma unroll
    for (int t = 0; t < 4; ++t) {
      int c = t * 256 + tid;
      int r = c >> 3;
      int gc = ((c & 7) ^ (r & 7)) << 3;
      async16(A + (m0 + r) * (size_t)K + k0 + gc, &As[c * 8]);
    }
#pragma unroll
    for (int t = 0; t < 4; ++t) {
      int c = t * 256 + tid;
      int r = c >> 3;
      int gc = ((c & 7) ^ (r & 7)) << 3;
      async16(B + (n0 + r) * (size_t)K + k0 + gc, &Bs[c * 8]);
    }
    __syncthreads();
#pragma unroll
    for (int c = 0; c < 4; ++c) {
      const int c8 = c * 2 + lh;
      short8 af[2], bfr[2];
#pragma unroll
      for (int mi = 0; mi < 2; ++mi) {
        int r = wr * 64 + mi * 32 + lr;
        af[mi] = *(const short8*)&As[r * 64 + ((c8 ^ (r & 7)) << 3)];
      }
#pragma unroll
      for (int ni = 0; ni < 2; ++ni) {
        int r = wc * 64 + ni * 32 + lr;
        bfr[ni] = *(const short8*)&Bs[r * 64 + ((c8 ^ (r & 7)) << 3)];
      }
#pragma unroll
      for (int mi = 0; mi < 2; ++mi)
#pragma unroll
        for (int ni = 0; ni < 2; ++ni)
          acc[mi][ni] = MFMA32(af[mi], bfr[ni], acc[mi][ni]);
    }
    __syncthreads();
  }
#pragma unroll
  for (int mi = 0; mi < 2; ++mi)
#pragma unroll
    for (int ni = 0; ni < 2; ++ni) {
      size_t n = n0 + wc * 64 + ni * 32 + lr;
#pragma unroll
      for (int reg = 0; reg < 16; ++reg) {
        size_t m = m0 + wr * 64 + mi * 32 + (reg & 3) + 8 * (reg >> 2) + 4 * lh;
        float v = acc[mi][ni][reg];
        if (MODE == 0)
          Cb[m * (size_t)N + n] = f2b(v);
        else
          Cf[m * (size_t)N + n] = v + R[m * (size_t)N + n];
      }
    }
}

// ---------------------------------------------------------------------------
// Fused SwiGLU GEMM — unchanged from round 1.
// ---------------------------------------------------------------------------
__global__ __launch_bounds__(256, 2) void ffn_gemm(
    const u16* __restrict__ A, const u16* __restrict__ B1,
    const u16* __restrict__ B3, u16* __restrict__ Hout, int M, int N, int K) {
  __shared__ __align__(16) u16 As[128 * 64];
  __shared__ __align__(16) u16 B1s[128 * 64];
  __shared__ __align__(16) u16 B3s[128 * 64];
  const int tid = threadIdx.x;
  const int l = tid & 63, w = tid >> 6;
  const int wr = w & 1, wc = w >> 1;
  const int lr = l & 31, lh = l >> 5;
  const size_t m0 = (size_t)blockIdx.y * 128, n0 = (size_t)blockIdx.x * 128;
  f32x16 a1[2][2] = {}, a3[2][2] = {};
  for (int k0 = 0; k0 < K; k0 += 64) {
#pragma unroll
    for (int t = 0; t < 4; ++t) {
      int c = t * 256 + tid;
      int r = c >> 3;
      int gc = ((c & 7) ^ (r & 7)) << 3;
      async16(A + (m0 + r) * (size_t)K + k0 + gc, &As[c * 8]);
      async16(B1 + (n0 + r) * (size_t)K + k0 + gc, &B1s[c * 8]);
      async16(B3 + (n0 + r) * (size_t)K + k0 + gc, &B3s[c * 8]);
    }
    __syncthreads();
#pragma unroll
    for (int c = 0; c < 4; ++c) {
      const int c8 = c * 2 + lh;
      short8 af[2], b1f[2], b3f[2];
#pragma unroll
      for (int mi = 0; mi < 2; ++mi) {
        int r = wr * 64 + mi * 32 + lr;
        af[mi] = *(const short8*)&As[r * 64 + ((c8 ^ (r & 7)) << 3)];
      }
#pragma unroll
      for (int ni = 0; ni < 2; ++ni) {
        int r = wc * 64 + ni * 32 + lr;
        b1f[ni] = *(const short8*)&B1s[r * 64 + ((c8 ^ (r & 7)) << 3)];
        b3f[ni] = *(const short8*)&B3s[r * 64 + ((c8 ^ (r & 7)) << 3)];
      }
#pragma unroll
      for (int mi = 0; mi < 2; ++mi)
#pragma unroll
        for (int ni = 0; ni < 2; ++ni) {
          a1[mi][ni] = MFMA32(af[mi], b1f[ni], a1[mi][ni]);
          a3[mi][ni] = MFMA32(af[mi], b3f[ni], a3[mi][ni]);
        }
    }
    __syncthreads();
  }
#pragma unroll
  for (int mi = 0; mi < 2; ++mi)
#pragma unroll
    for (int ni = 0; ni < 2; ++ni) {
      size_t n = n0 + wc * 64 + ni * 32 + lr;
#pragma unroll
      for (int reg = 0; reg < 16; ++reg) {
        size_t m = m0 + wr * 64 + mi * 32 + (reg & 3) + 8 * (reg >> 2) + 4 * lh;
        float u = a1[mi][ni][reg];
        float g = u / (1.0f + __expf(-u));  // silu
        Hout[m * (size_t)N + n] = f2b(g * a3[mi][ni][reg]);
      }
    }
}

// ---------------------------------------------------------------------------
// Flash attention v4 (causal), S^T formulation, q-tile 128.
// Block: 128 q-cols (4 waves x 2 subtiles of 16), KV tiles of 128.
// Each KV stage (Ks 128x64 + Vs 64x128, async16) is shared by BOTH q-subtiles:
// staging traffic and barriers halve vs R3. Ps rows are wave-private and
// reused serially per subtile (in-wave lgkmcnt ordering). LDS 49KB.
// ---------------------------------------------------------------------------
__global__ __launch_bounds__(256, 2) void attn_k(
    const u16* __restrict__ qh, const u16* __restrict__ kh,
    const u16* __restrict__ vt, u16* __restrict__ aout) {
  __shared__ __align__(16) u16 Ks[128 * 64];
  __shared__ __align__(16) u16 Vs[64 * 128];
  __shared__ __align__(16) u16 Ps[64 * 136];
  const int tid = threadIdx.x;
  const int l = tid & 63, w = tid >> 6;
  const int q = l & 15, lq = l >> 4;
  const int q0 = (int)(gridDim.x - 1 - blockIdx.x) * 128;  // heavy blocks first
  const int bh = blockIdx.y;
  const size_t base = (size_t)bh * (2048 * 64);
  const int nt = (q0 >> 7) + 1;

  // two q-subtile columns per wave
  int qcol[2] = {q0 + w * 16 + q, q0 + 64 + w * 16 + q};
  short8 bq[2][2];
#pragma unroll
  for (int sub = 0; sub < 2; ++sub)
#pragma unroll
    for (int kk = 0; kk < 2; ++kk)
      bq[sub][kk] = *(const short8*)(qh + base + (size_t)qcol[sub] * 64 + kk * 32 + lq * 8);

  f32x4 o[2][4] = {};
  float mI[2] = {-1e30f, -1e30f}, lI[2] = {0.0f, 0.0f};
  u16* pr = &Ps[(w * 16 + q) * 136];

  for (int it = 0; it < nt; ++it) {
    const int kv0 = it << 7;
    if (it) __syncthreads();  // WAR: all waves done with previous tile
#pragma unroll
    for (int t = 0; t < 4; ++t) {
      int p = t * 256 + tid;
      int r = p >> 3, cs = p & 7;
      async16(kh + base + (size_t)(kv0 + r) * 64 + ((cs ^ (r & 7)) << 3), &Ks[p * 8]);
    }
#pragma unroll
    for (int t = 0; t < 4; ++t) {
      int p = t * 256 + tid;
      int r = p >> 4, cs = p & 15;
      async16(vt + base + (size_t)r * 2048 + kv0 + ((cs ^ (r & 15)) << 3), &Vs[p * 8]);
    }
    __syncthreads();
    const bool last = (it == nt - 1);
#pragma unroll
    for (int sub = 0; sub < 2; ++sub) {
      // S^T = K · Q^T : 8 kv-subtiles of 16
      f32x4 s[8] = {};
#pragma unroll
      for (int kk = 0; kk < 2; ++kk) {
#pragma unroll
        for (int mt = 0; mt < 8; ++mt) {
          int row = mt * 16 + q;
          short8 ak = *(const short8*)&Ks[row * 64 + (((kk * 4 + lq) ^ (q & 7)) << 3)];
          s[mt] = MFMA16(ak, bq[sub][kk], s[mt]);
        }
      }
      if (last) {  // causal mask (sub0 also masks the fully-future upper half)
#pragma unroll
        for (int mt = 0; mt < 8; ++mt)
#pragma unroll
          for (int r = 0; r < 4; ++r)
            if (kv0 + mt * 16 + lq * 4 + r > qcol[sub]) s[mt][r] = -1e30f;
      }
      // online softmax, exp2 domain, per-lane scalars (Q prescaled in rope_k)
      float mx = -1e30f;
#pragma unroll
      for (int mt = 0; mt < 8; ++mt)
#pragma unroll
        for (int r = 0; r < 4; ++r) mx = fmaxf(mx, s[mt][r]);
      mx = fmaxf(mx, __shfl_xor(mx, 16, 64));
      mx = fmaxf(mx, __shfl_xor(mx, 32, 64));
      const float mn = fmaxf(mI[sub], mx);
      const float al = exp2f(mI[sub] - mn);
      mI[sub] = mn;
      float rs = 0.0f;
#pragma unroll
      for (int mt = 0; mt < 8; ++mt)
#pragma unroll
        for (int r = 0; r < 4; ++r) {
          float p = exp2f(s[mt][r] - mn);
          s[mt][r] = p;
          rs += p;
        }
      rs += __shfl_xor(rs, 16, 64);
      rs += __shfl_xor(rs, 32, 64);
      lI[sub] = lI[sub] * al + rs;
#pragma unroll
      for (int mt = 0; mt < 4; ++mt)
#pragma unroll
        for (int r = 0; r < 4; ++r) o[sub][mt][r] *= al;
      // P^T -> Ps[q-local][kv] (wave-private rows; b64 writes)
#pragma unroll
      for (int mt = 0; mt < 8; ++mt) {
        uint2 pd;
        pd.x = pkbf(s[mt][0], s[mt][1]);
        pd.y = pkbf(s[mt][2], s[mt][3]);
        *(uint2*)&pr[mt * 16 + lq * 4] = pd;
      }
      // O^T += V^T · P^T
#pragma unroll
      for (int kk = 0; kk < 4; ++kk) {
        short8 bp = *(const short8*)&pr[kk * 32 + lq * 8];
#pragma unroll
        for (int mt = 0; mt < 4; ++mt) {
          int row = mt * 16 + q;
          short8 av = *(const short8*)&Vs[row * 128 + (((kk * 4 + lq) ^ (row & 15)) << 3)];
          o[sub][mt] = MFMA16(av, bp, o[sub][mt]);
        }
      }
    }
  }
  const int b = bh >> 4, h = bh & 15;
#pragma unroll
  for (int sub = 0; sub < 2; ++sub) {
    const float inv = 1.0f / lI[sub];
#pragma unroll
    for (int mt = 0; mt < 4; ++mt) {
      uint2 pd;
      pd.x = pkbf(o[sub][mt][0] * inv, o[sub][mt][1] * inv);
      pd.y = pkbf(o[sub][mt][2] * inv, o[sub][mt][3] * inv);
      *(uint2*)&aout[((size_t)(b * 2048 + qcol[sub])) * 1024 + h * 64 + mt * 16 + lq * 4] = pd;
    }
  }
}

// ---------------------------------------------------------------------------
// Elementwise helpers
// ---------------------------------------------------------------------------
__global__ __launch_bounds__(256) void rmsnorm_k(
    const float* __restrict__ x, const float* __restrict__ w, u16* __restrict__ out) {
  const int row = blockIdx.x;
  const int tid = threadIdx.x;
  const float4 v = ((const float4*)(x + (size_t)row * 1024))[tid];
  float ss = v.x * v.x + v.y * v.y + v.z * v.z + v.w * v.w;
#pragma unroll
  for (int d = 1; d < 64; d <<= 1) ss += __shfl_xor(ss, d, 64);
  __shared__ float red[4];
  if ((tid & 63) == 0) red[tid >> 6] = ss;
  __syncthreads();
  const float sc = rsqrtf((red[0] + red[1] + red[2] + red[3]) * (1.0f / 1024.0f) + 1e-5f);
  const float4 wv = ((const float4*)w)[tid];
  u16* o = out + (size_t)row * 1024 + tid * 4;
  o[0] = f2b(v.x * sc * wv.x);
  o[1] = f2b(v.y * sc * wv.y);
  o[2] = f2b(v.z * sc * wv.z);
  o[3] = f2b(v.w * sc * wv.w);
}

// RoPE for q AND k from fused QKV [8192][3072] -> QH/KH [b][h][s][64].
// Vectorized: one lane = 8 u16 (4 rope pairs), uint4 load/store.
// Q prescaled by 0.125*log2(e) -> exp2-domain softmax.
__global__ __launch_bounds__(256) void rope_k(
    const u16* __restrict__ qkv, u16* __restrict__ qh, u16* __restrict__ kh,
    const int* __restrict__ pos) {
  int idx = blockIdx.x * 256 + threadIdx.x;  // 8192 rows * 256 groups
  int grp = idx & 255;
  int row = idx >> 8;
  int which = grp >> 7;  // 0=q, 1=k
  int p = grp & 127;
  int s = row & 2047, b = row >> 11;
  int h = p >> 3, gi = p & 7;
  const u16* src = qkv + (size_t)row * 3072 + which * 1024 + h * 64 + gi * 8;
  uint4 in = *(const uint4*)src;
  const u16* e = (const u16*)&in;
  const float fp = (float)pos[s];
  const float scale = which ? 1.0f : 0.18033688011112042f;  // 0.125*log2(e)
  uint4 outv;
  unsigned* ov = (unsigned*)&outv;
#pragma unroll
  for (int j = 0; j < 4; ++j) {
    int i = gi * 4 + j;  // pair index 0..31
    float xe = b2f(e[2 * j]), xo = b2f(e[2 * j + 1]);
    float inv = exp2f(-(float)(2 * i) * (13.287712379549449f / 64.0f));
    float ang = fp * inv;
    float sn, cs;
    __sincosf(ang, &sn, &cs);
    ov[j] = pkbf((xe * cs - xo * sn) * scale, (xe * sn + xo * cs) * scale);
  }
  u16* dst = (which ? kh : qh) + (((size_t)(b * 16 + h)) * 2048 + s) * 64 + gi * 8;
  *(uint4*)dst = outv;
}

// v (cols 2048..3071 of QKV) -> vT [b][h][d][s], 64x64 LDS tile transpose
__global__ __launch_bounds__(256) void transv_k(
    const u16* __restrict__ qkv, u16* __restrict__ vt) {
  __shared__ u16 t[64][65];
  const int bh = blockIdx.y, s0 = blockIdx.x * 64;
  const int b = bh >> 4, h = bh & 15;
  const int tid = threadIdx.x;
#pragma unroll
  for (int i = 0; i < 16; ++i) {
    int e = i * 256 + tid;
    int sl = e >> 6, d = e & 63;
    t[sl][d] = qkv[((size_t)(b * 2048 + s0 + sl)) * 3072 + 2048 + h * 64 + d];
  }
  __syncthreads();
#pragma unroll
  for (int i = 0; i < 16; ++i) {
    int e = i * 256 + tid;
    int d = e >> 6, sl = e & 63;
    vt[((size_t)(bh * 64 + d)) * 2048 + s0 + sl] = t[sl][d];
  }
}

// All 7 weight tensors fp32->bf16 in one launch.
// Segments: qp,kp,vp,op (262144 float4-groups each, dst WQKV/WO contiguous),
// then w1,w3,w2 (1048576 groups each).
__global__ __launch_bounds__(256) void cvt_all(
    const float* __restrict__ qp, const float* __restrict__ kp,
    const float* __restrict__ vp, const float* __restrict__ op,
    const float* __restrict__ w1, const float* __restrict__ w3,
    const float* __restrict__ w2,
    u16* __restrict__ WQKV, u16* __restrict__ WO,
    u16* __restrict__ W1, u16* __restrict__ W3, u16* __restrict__ W2) {
  int i = blockIdx.x * 256 + threadIdx.x;  // [0, 4194304)
  const float* src;
  u16* dst;
  int off;
  if (i < 1048576) {
    int seg = i >> 18, within = i & 262143;
    src = (seg == 0) ? qp : (seg == 1) ? kp : (seg == 2) ? vp : op;
    dst = (seg == 3) ? WO : WQKV + (size_t)seg * 1048576;
    off = within;
  } else {
    int j = i - 1048576;
    int seg = j >> 20;
    off = j & 1048575;
    src = (seg == 0) ? w1 : (seg == 1) ? w3 : w2;
    dst = (seg == 0) ? W1 : (seg == 1) ? W3 : W2;
  }
  float4 v = ((const float4*)src)[off];
  u16* o = dst + (size_t)off * 4;
  o[0] = f2b(v.x); o[1] = f2b(v.y); o[2] = f2b(v.z); o[3] = f2b(v.w);
}

// ---------------------------------------------------------------------------
extern "C" void kernel_launch(void* const* d_in, const int* in_sizes, int n_in,
                              void* d_out, int out_size, void* d_ws, size_t ws_size,
                              hipStream_t stream) {
  const float* x   = (const float*)d_in[0];
  const int*   pos = (const int*)d_in[1];
  const float* qp  = (const float*)d_in[2];
  const float* kp  = (const float*)d_in[3];
  const float* vp  = (const float*)d_in[4];
  const float* op  = (const float*)d_in[5];
  const float* w1  = (const float*)d_in[6];
  const float* w2  = (const float*)d_in[7];   // dict order: w2 before w3
  const float* w3  = (const float*)d_in[8];
  const float* ln1 = (const float*)d_in[9];
  const float* ln2 = (const float*)d_in[10];
  float* out = (float*)d_out;
  char* ws = (char*)d_ws;
  const size_t MB = 1024 * 1024;

  u16* WQKV = (u16*)(ws + 0 * MB);    // [3072][1024] stacked q,k,v  (6 MB)
  u16* WO   = (u16*)(ws + 6 * MB);
  u16* W1   = (u16*)(ws + 8 * MB);
  u16* W3   = (u16*)(ws + 16 * MB);
  u16* W2   = (u16*)(ws + 24 * MB);
  u16* XLN  = (u16*)(ws + 32 * MB);
  u16* QKV  = (u16*)(ws + 48 * MB);   // [8192][3072]  (48..96 MB)
  u16* QH   = (u16*)(ws + 96 * MB);
  u16* KH   = (u16*)(ws + 112 * MB);
  u16* VT   = (u16*)(ws + 128 * MB);
  u16* ATT  = (u16*)(ws + 48 * MB);   // reuses QKV
  u16* XLN2 = (u16*)(ws + 64 * MB);
  u16* Hbuf = (u16*)(ws + 80 * MB);   // 64 MB (VT dead by then)
  (void)in_sizes; (void)n_in; (void)out_size; (void)ws_size;

  cvt_all<<<16384, 256, 0, stream>>>(qp, kp, vp, op, w1, w3, w2,
                                     WQKV, WO, W1, W3, W2);
  rmsnorm_k<<<8192, 256, 0, stream>>>(x, ln1, XLN);
  gemm_bt<0><<<dim3(24, 64), 256, 0, stream>>>(XLN, WQKV, QKV, nullptr, nullptr, 8192, 3072, 1024);
  rope_k<<<8192, 256, 0, stream>>>(QKV, QH, KH, pos);
  transv_k<<<dim3(32, 64), 256, 0, stream>>>(QKV, VT);
  attn_k<<<dim3(16, 64), 256, 0, stream>>>(QH, KH, VT, ATT);
  gemm_bt<1><<<dim3(8, 64), 256, 0, stream>>>(ATT, WO, nullptr, out, x, 8192, 1024, 1024);
  rmsnorm_k<<<8192, 256, 0, stream>>>(out, ln2, XLN2);
  ffn_gemm<<<dim3(32, 64), 256, 0, stream>>>(XLN2, W1, W3, Hbuf, 8192, 4096, 1024);
  gemm_bt<1><<<dim3(8, 64), 256, 0, stream>>>(Hbuf, W2, nullptr, out, out, 8192, 1024, 4096);
}